// Round 7
// baseline (100.013 us; speedup 1.0000x reference)
//
#include <hip/hip_runtime.h>

typedef __attribute__((ext_vector_type(4))) float f32x4;
typedef __attribute__((ext_vector_type(8))) __bf16 bf16x8;
typedef __attribute__((ext_vector_type(8))) unsigned short ushort8v;

#define NGRP   100
#define DDIM   768
#define FDIM   100
#define NCLS   10000
#define NSTEP  12                       // 768 / 64
#define NCHUNK 14                       // 7 f-tiles x 2 k-halves
#define CH_SHORTS 512                   // one chunk: 64 lanes x 8 bf16 (16 B/lane)
#define STEP_SHORTS (NCHUNK * CH_SHORTS)   // 7168 shorts = 14336 B per k-step
#define G_SHORTS (NSTEP * STEP_SHORTS)     // 86016 shorts per group (168 KB)

static __device__ __forceinline__ unsigned short f2bf(float f) {
    __bf16 b = (__bf16)f;   // RNE; pairs into v_cvt_pk_bf16_f32
    return __builtin_bit_cast(unsigned short, b);
}

// ---- pre-pass: W (g,d,f) f32 -> Wt fragment-linear bf16 (unchanged, verified) ----
// Wt[g][step][c][lane][j] = W[g][step*64 + (c&1)*32 + (lane>>4)*8 + j][min((c>>1)*16 + (lane&15), 99)]
__global__ __launch_bounds__(256) void build_wt(
    const float* __restrict__ W, unsigned short* __restrict__ Wt)
{
    __shared__ unsigned short lt[FDIM * 66];   // [f][d-offset], 33-dword stride: conflict-free
    const int b = blockIdx.x, g = b / 12, step = b % 12;
    const int tid = threadIdx.x;

    const float* Wg = W + (size_t)g * (DDIM * FDIM) + (size_t)step * 64 * FDIM;
#pragma unroll
    for (int j = 0; j < 25; ++j) {          // 64 d-rows x 100 f, coalesced reads
        const int i = tid + j * 256;
        const int r = i / 100, f = i % 100;
        lt[f * 66 + r] = f2bf(Wg[i]);
    }
    __syncthreads();

    unsigned short* out = Wt + (size_t)g * G_SHORTS + step * STEP_SHORTS;
#pragma unroll
    for (int j = 0; j < 4; ++j) {
        const int idx = tid + j * 256;      // 0..895 fragment-lane slots
        if (idx < NCHUNK * 64) {
            const int c = idx >> 6, lane = idx & 63;
            const int t = c >> 1, half = c & 1;
            int f = t * 16 + (lane & 15); if (f > FDIM - 1) f = FDIM - 1;
            const int kk = half * 32 + (lane >> 4) * 8;
            const unsigned short* src = &lt[f * 66 + kk];
            ushort8v v;
            v[0]=src[0]; v[1]=src[1]; v[2]=src[2]; v[3]=src[3];
            v[4]=src[4]; v[5]=src[5]; v[6]=src[6]; v[7]=src[7];
            *(ushort8v*)(out + (size_t)idx * 8) = v;    // coalesced 16B stores
        }
    }
}

// ---- per-wave pipeline: TB = first f-tile, TCNT = tiles owned by this wave ----
template<int TB, int TCNT>
__device__ __forceinline__ void wave_main(
    const float* __restrict__ Ap, const unsigned short* __restrict__ Bg,
    const float* __restrict__ Bv, float* __restrict__ Out,
    int m0, int fbase, int lane)
{
    const int r16 = lane & 15;
    const int kg  = lane >> 4;

    f32x4 acc[TCNT];
#pragma unroll
    for (int t = 0; t < TCNT; ++t) acc[t] = (f32x4)(0.0f);

    f32x4 a0[4], a1[4];                  // A slots, distance 2
    ushort8v b0[2 * TCNT], b1[2 * TCNT]; // B slots, distance 1

#define LOADA_(SL, STEP) do { \
        const float* p_ = Ap + (STEP) * 64; \
        SL[0] = *(const f32x4*)(p_); \
        SL[1] = *(const f32x4*)(p_ + 4); \
        SL[2] = *(const f32x4*)(p_ + 32); \
        SL[3] = *(const f32x4*)(p_ + 36); \
    } while (0)
#define LOADB_(SL, STEP) do { \
        const unsigned short* q_ = Bg + (size_t)(STEP) * STEP_SHORTS; \
        _Pragma("unroll") \
        for (int c_ = 0; c_ < 2 * TCNT; ++c_) \
            SL[c_] = *(const ushort8v*)(q_ + (2 * TB + c_) * CH_SHORTS); \
    } while (0)
#define COMPUTE_(ASL, BSL) do { \
        _Pragma("unroll") \
        for (int s_ = 0; s_ < 2; ++s_) { \
            ushort8v u_; \
            _Pragma("unroll") \
            for (int j_ = 0; j_ < 4; ++j_) { \
                u_[j_]     = f2bf(ASL[2*s_][j_]); \
                u_[j_ + 4] = f2bf(ASL[2*s_+1][j_]); \
            } \
            const bf16x8 af_ = __builtin_bit_cast(bf16x8, u_); \
            _Pragma("unroll") \
            for (int t_ = 0; t_ < TCNT; ++t_) \
                acc[t_] = __builtin_amdgcn_mfma_f32_16x16x32_bf16( \
                    af_, __builtin_bit_cast(bf16x8, BSL[t_*2 + s_]), acc[t_], 0, 0, 0); \
        } \
    } while (0)

    // prologue: A dist-2, B dist-1; fence pins issue order (no sinking)
    LOADA_(a0, 0);
    LOADA_(a1, 1);
    LOADB_(b0, 0);
    __builtin_amdgcn_sched_barrier(0);

#pragma unroll
    for (int t = 0; t < NSTEP; ++t) {
        if (t + 1 < NSTEP) {
            if ((t & 1) == 0) LOADB_(b1, t + 1); else LOADB_(b0, t + 1);
            __builtin_amdgcn_sched_barrier(0);   // next-B stays issued before compute
        }
        if ((t & 1) == 0) { COMPUTE_(a0, b0); if (t + 2 < NSTEP) LOADA_(a0, t + 2); }
        else              { COMPUTE_(a1, b1); if (t + 2 < NSTEP) LOADA_(a1, t + 2); }
        __builtin_amdgcn_sched_barrier(0);       // A-refill stays in this step
    }
#undef LOADA_
#undef LOADB_
#undef COMPUTE_

    // epilogue: C/D layout col=lane&15, row=(lane>>4)*4+r
    const int orow = m0 + kg * 4;
#pragma unroll
    for (int tt = 0; tt < TCNT; ++tt) {
        const int fc = (TB + tt) * 16 + r16;
        if (fc < FDIM) {
            const float bv = Bv[fbase + fc];
#pragma unroll
            for (int r = 0; r < 4; ++r)
                Out[(size_t)(orow + r) * NCLS + fbase + fc] = acc[tt][r] + bv;
        }
    }
}

// ---- main: 4 waves/block, split-F (2/2/2/1 tiles), no LDS, no barriers ----
__global__ __launch_bounds__(256, 4) void gfcp_main(
    const float* __restrict__ H, const unsigned short* __restrict__ Wt,
    const float* __restrict__ Bv, float* __restrict__ Out)
{
    // 3200 blocks = 100 groups x 32 m-tiles of 16 rows; 3200 % 8 == 0.
    // XCD-bijective swizzle: 400 contiguous wgids per XCD (group Wt slice 2.1 MB in L2).
    const int bid  = blockIdx.x;
    const int wgid = (bid & 7) * 400 + (bid >> 3);
    const int g    = wgid >> 5;           // group 0..99
    const int m0   = (wgid & 31) * 16;    // row tile 0..496

    const int tid  = threadIdx.x;
    const int lane = tid & 63;
    const int wv   = tid >> 6;            // 0..3
    const int r16  = lane & 15;
    const int kg   = lane >> 4;

    const float* Ap = H + (size_t)(m0 + r16) * (NGRP * DDIM)
                        + (size_t)g * DDIM + kg * 8;
    const unsigned short* Bg = Wt + (size_t)g * G_SHORTS + lane * 8;
    const int fbase = g * FDIM;

    if      (wv == 0) wave_main<0, 2>(Ap, Bg, Bv, Out, m0, fbase, lane);
    else if (wv == 1) wave_main<2, 2>(Ap, Bg, Bv, Out, m0, fbase, lane);
    else if (wv == 2) wave_main<4, 2>(Ap, Bg, Bv, Out, m0, fbase, lane);
    else              wave_main<6, 1>(Ap, Bg, Bv, Out, m0, fbase, lane);
}

extern "C" void kernel_launch(void* const* d_in, const int* in_sizes, int n_in,
                              void* d_out, int out_size, void* d_ws, size_t ws_size,
                              hipStream_t stream) {
    const float* H  = (const float*)d_in[0];   // (512, 100, 768) f32
    const float* W  = (const float*)d_in[1];   // (100, 768, 100) f32
    const float* Bv = (const float*)d_in[2];   // (10000,) f32
    float* Out = (float*)d_out;                // (512, 10000) f32
    unsigned short* Wt = (unsigned short*)d_ws; // fragment-linear bf16, 17.2 MB

    build_wt<<<dim3(1200), dim3(256), 0, stream>>>(W, Wt);
    gfcp_main<<<dim3(3200), dim3(256), 0, stream>>>(H, Wt, Bv, Out);
}

// Round 8
// 49.321 us; speedup vs baseline: 2.0278x; 2.0278x over previous
//
#include <hip/hip_runtime.h>

typedef __attribute__((ext_vector_type(4))) float f32x4;
typedef __attribute__((ext_vector_type(8))) __bf16 bf16x8;
typedef __attribute__((ext_vector_type(8))) unsigned short ushort8v;

#define NGRP   100
#define DDIM   768
#define FDIM   100
#define NCLS   10000
#define NSTEP  12                       // 768 / 64
#define NTILE  7                        // ceil(112/16) f-tiles
#define NCHUNK 14                       // 7 f-tiles x 2 k-halves (7 per wave)
#define CH_SHORTS 512                   // one chunk: 64 lanes x 8 bf16 (16 B/lane)
#define STEP_SHORTS (NCHUNK * CH_SHORTS)   // 7168 shorts = 14336 B per k-step
#define G_SHORTS (NSTEP * STEP_SHORTS)     // 86016 shorts per group (168 KB)

#define GLOBAL_AS __attribute__((address_space(1)))
#define LDS_AS    __attribute__((address_space(3)))

static __device__ __forceinline__ unsigned short f2bf(float f) {
    __bf16 b = (__bf16)f;   // RNE; pairs into v_cvt_pk_bf16_f32
    return __builtin_bit_cast(unsigned short, b);
}

// ---- pre-pass: W (g,d,f) f32 -> Wt fragment-linear bf16 (unchanged, verified) ----
// Wt[g][step][c][lane][j] = W[g][step*64 + (c&1)*32 + (lane>>4)*8 + j][min((c>>1)*16 + (lane&15), 99)]
__global__ __launch_bounds__(256) void build_wt(
    const float* __restrict__ W, unsigned short* __restrict__ Wt)
{
    __shared__ unsigned short lt[FDIM * 66];   // [f][d-offset], 33-dword stride: conflict-free
    const int b = blockIdx.x, g = b / 12, step = b % 12;
    const int tid = threadIdx.x;

    const float* Wg = W + (size_t)g * (DDIM * FDIM) + (size_t)step * 64 * FDIM;
#pragma unroll
    for (int j = 0; j < 25; ++j) {          // 64 d-rows x 100 f, coalesced reads
        const int i = tid + j * 256;
        const int r = i / 100, f = i % 100;
        lt[f * 66 + r] = f2bf(Wg[i]);
    }
    __syncthreads();

    unsigned short* out = Wt + (size_t)g * G_SHORTS + step * STEP_SHORTS;
#pragma unroll
    for (int j = 0; j < 4; ++j) {
        const int idx = tid + j * 256;      // 0..895 fragment-lane slots
        if (idx < NCHUNK * 64) {
            const int c = idx >> 6, lane = idx & 63;
            const int t = c >> 1, half = c & 1;
            int f = t * 16 + (lane & 15); if (f > FDIM - 1) f = FDIM - 1;
            const int kk = half * 32 + (lane >> 4) * 8;
            const unsigned short* src = &lt[f * 66 + kk];
            ushort8v v;
            v[0]=src[0]; v[1]=src[1]; v[2]=src[2]; v[3]=src[3];
            v[4]=src[4]; v[5]=src[5]; v[6]=src[6]; v[7]=src[7];
            *(ushort8v*)(out + (size_t)idx * 8) = v;    // coalesced 16B stores
        }
    }
}

// ---- main: 128 thr / 2 waves / 2 M-tiles per wave; dbuf DMA; counted vmcnt;
// ---- A-prefetch PINNED in VGPRs via volatile asm (anti-sinking) ----
__global__ __launch_bounds__(128, 3) void gfcp_main(
    const float* __restrict__ H, const unsigned short* __restrict__ Wt,
    const float* __restrict__ Bv, float* __restrict__ Out)
{
    __shared__ unsigned short Bl[2][STEP_SHORTS];   // 2 x 14 KB = 28 KB -> 5 blocks/CU

    // XCD-bijective swizzle (800 % 8 == 0): a group's 8 row-blocks share one XCD L2
    const int bid  = blockIdx.x;
    const int wgid = (bid & 7) * 100 + (bid >> 3);
    const int g    = wgid >> 3;
    const int m0   = (wgid & 7) * 64;

    const int tid  = threadIdx.x;
    const int lane = tid & 63;
    const int wv   = tid >> 6;            // 0..1
    const int r16  = lane & 15;
    const int kg   = lane >> 4;

    const float* Ap0 = H + (size_t)(m0 + wv * 32 + r16) * (NGRP * DDIM)
                         + (size_t)g * DDIM + kg * 8;
    const float* Ap1 = Ap0 + (size_t)16 * (NGRP * DDIM);
    const unsigned short* Bg = Wt + (size_t)g * G_SHORTS + lane * 8;

    f32x4 acc[2][NTILE];
#pragma unroll
    for (int at = 0; at < 2; ++at)
#pragma unroll
        for (int t = 0; t < NTILE; ++t) acc[at][t] = (f32x4)(0.0f);

    f32x4 a[2][2][4];   // [slot][A-tile][4x f32x4]

    auto stage = [&](int buf, int step) {   // exactly 7 DMA per wave (no dest reg -> unsinkable)
        const unsigned short* gsrc = Bg + step * STEP_SHORTS;
#pragma unroll
        for (int i = 0; i < 7; ++i) {
            const int c = wv * 7 + i;       // wave-uniform chunk id, 0..13
            __builtin_amdgcn_global_load_lds(
                (const GLOBAL_AS void*)(gsrc + c * CH_SHORTS),
                (LDS_AS void*)(&Bl[buf][c * CH_SHORTS]),
                16, 0, 0);
        }
    };
    auto loadA = [&](int slot, int step) {  // exactly 8 global_load_dwordx4, then PIN
        const float* p0 = Ap0 + step * 64;
        a[slot][0][0] = *(const f32x4*)(p0);
        a[slot][0][1] = *(const f32x4*)(p0 + 4);
        a[slot][0][2] = *(const f32x4*)(p0 + 32);
        a[slot][0][3] = *(const f32x4*)(p0 + 36);
        const float* p1 = Ap1 + step * 64;
        a[slot][1][0] = *(const f32x4*)(p1);
        a[slot][1][1] = *(const f32x4*)(p1 + 4);
        a[slot][1][2] = *(const f32x4*)(p1 + 32);
        a[slot][1][3] = *(const f32x4*)(p1 + 36);
        // PIN: force loads issued HERE, results held in VGPRs until use.
        asm volatile("" : "+v"(a[slot][0][0]), "+v"(a[slot][0][1]),
                          "+v"(a[slot][0][2]), "+v"(a[slot][0][3]),
                          "+v"(a[slot][1][0]), "+v"(a[slot][1][1]),
                          "+v"(a[slot][1][2]), "+v"(a[slot][1][3]));
    };
    auto compute = [&](int buf, int slot) { // 14 ds_read_b128 -> 28 MFMA
        const unsigned short* bl = &Bl[buf][0];
#pragma unroll
        for (int s = 0; s < 2; ++s) {
            ushort8v u0, u1;
#pragma unroll
            for (int j = 0; j < 4; ++j) {
                u0[j]   = f2bf(a[slot][0][2*s][j]); u0[j+4] = f2bf(a[slot][0][2*s+1][j]);
                u1[j]   = f2bf(a[slot][1][2*s][j]); u1[j+4] = f2bf(a[slot][1][2*s+1][j]);
            }
            const bf16x8 af0 = __builtin_bit_cast(bf16x8, u0);
            const bf16x8 af1 = __builtin_bit_cast(bf16x8, u1);
#pragma unroll
            for (int t = 0; t < NTILE; ++t) {
                const ushort8v bu = *(const ushort8v*)(bl + (t * 2 + s) * CH_SHORTS + lane * 8);
                const bf16x8 bf = __builtin_bit_cast(bf16x8, bu);
                acc[0][t] = __builtin_amdgcn_mfma_f32_16x16x32_bf16(af0, bf, acc[0][t], 0, 0, 0);
                acc[1][t] = __builtin_amdgcn_mfma_f32_16x16x32_bf16(af1, bf, acc[1][t], 0, 0, 0);
            }
        }
    };

    // ---- prologue: A(0)[8 pinned], S(0)[7], A(1)[8 pinned]; wait A(0)+S(0) -> vmcnt(8) ----
    loadA(0, 0);
    __builtin_amdgcn_sched_barrier(0);
    stage(0, 0);
    __builtin_amdgcn_sched_barrier(0);
    loadA(1, 1);
    __builtin_amdgcn_sched_barrier(0);
    asm volatile("s_waitcnt vmcnt(8)" ::: "memory");
    __builtin_amdgcn_s_barrier();
    __builtin_amdgcn_sched_barrier(0);

    // ---- main loop (fully unrolled): never drain vmcnt in steady state ----
#pragma unroll
    for (int t = 0; t < NSTEP; ++t) {
        const int cur = t & 1;
        if (t + 1 < NSTEP) {
            stage(cur ^ 1, t + 1);          // issue next-step DMA into free buffer
            __builtin_amdgcn_sched_barrier(0);
        }
        compute(cur, cur);                  // ds_read + MFMA on current buffer
        if (t + 2 < NSTEP) loadA(cur, t + 2);   // refill freed A slot (pinned at issue)
        if (t + 1 < NSTEP) {
            __builtin_amdgcn_sched_barrier(0);
            // S(t+1) complete: ops newer than it = loadA(t+2) (8) if issued
            if (t + 2 < NSTEP) asm volatile("s_waitcnt vmcnt(8)" ::: "memory");
            else               asm volatile("s_waitcnt vmcnt(0)" ::: "memory");
            __builtin_amdgcn_s_barrier();
            __builtin_amdgcn_sched_barrier(0);  // ds_reads stay behind barrier
        }
    }

    // ---- epilogue: C/D layout col=lane&15, row=(lane>>4)*4+r ----
    const int fbase = g * FDIM;
#pragma unroll
    for (int at = 0; at < 2; ++at) {
        const int orow = m0 + wv * 32 + at * 16 + kg * 4;
#pragma unroll
        for (int t = 0; t < NTILE; ++t) {
            const int fc = t * 16 + r16;
            if (fc < FDIM) {
                const float bv = Bv[fbase + fc];
#pragma unroll
                for (int r = 0; r < 4; ++r) {
                    Out[(size_t)(orow + r) * NCLS + fbase + fc] = acc[at][t][r] + bv;
                }
            }
        }
    }
}

extern "C" void kernel_launch(void* const* d_in, const int* in_sizes, int n_in,
                              void* d_out, int out_size, void* d_ws, size_t ws_size,
                              hipStream_t stream) {
    const float* H  = (const float*)d_in[0];   // (512, 100, 768) f32
    const float* W  = (const float*)d_in[1];   // (100, 768, 100) f32
    const float* Bv = (const float*)d_in[2];   // (10000,) f32
    float* Out = (float*)d_out;                // (512, 10000) f32
    unsigned short* Wt = (unsigned short*)d_ws; // fragment-linear bf16, 17.2 MB

    build_wt<<<dim3(1200), dim3(256), 0, stream>>>(W, Wt);
    gfcp_main<<<dim3(800), dim3(128), 0, stream>>>(H, Wt, Bv, Out);
}